// Round 4
// baseline (1823.537 us; speedup 1.0000x reference)
//
#include <hip/hip_runtime.h>

#define T_SEQ 2048
#define NHEADS 8
#define NKV 4
#define HD 256
#define WIN 512

typedef __bf16 bf16x8 __attribute__((ext_vector_type(8)));
typedef float f32x4 __attribute__((ext_vector_type(4)));

__device__ __forceinline__ float bf2f(unsigned short u) {
    return __uint_as_float(((unsigned int)u) << 16);
}
__device__ __forceinline__ unsigned short f2bf(float f) {
    unsigned int u = __float_as_uint(f);
    u += 0x7fffu + ((u >> 16) & 1u);
    return (unsigned short)(u >> 16);
}

// ------------------------------------------------------------- dtype detect
// flag=1 if input is bf16, 0 if f32 (expected: 0). Samples even ushort
// indices of x: bf16 gaussian -> exponent field in [100,140] nearly always;
// f32 low-mantissa halves -> uniform (~16% in band).
__global__ void detect_dtype(const unsigned short* __restrict__ x, int* flag) {
    int tid = threadIdx.x;
    int cnt = 0;
    for (int i = 0; i < 64; ++i) {
        unsigned short u = x[2 * (tid * 64 + i)];
        int e = (u >> 7) & 0xFF;
        cnt += (e >= 100 && e <= 140) ? 1 : 0;
    }
    #pragma unroll
    for (int o = 32; o >= 1; o >>= 1) cnt += __shfl_xor(cnt, o);
    if (tid == 0) *flag = (cnt > 2048) ? 1 : 0;
}

// ------------------------------------------------------------- convert
__global__ __launch_bounds__(256) void convert_to_bf16(
    const void* __restrict__ src, unsigned short* __restrict__ dst,
    const int* __restrict__ flag, int n)
{
    int i = (blockIdx.x * 256 + threadIdx.x) * 8;
    if (i >= n) return;
    if (*flag) {
        *(uint4*)&dst[i] = *(const uint4*)((const unsigned short*)src + i);
    } else {
        const float* s = (const float*)src + i;
        unsigned short v[8];
        #pragma unroll
        for (int j = 0; j < 8; ++j) v[j] = f2bf(s[j]);
        *(uint4*)&dst[i] = *(uint4*)v;
    }
}

// ------------------------------------------------------------- transpose+cvt
// dst (C x R) bf16 = cast(src (R x C))^T
__global__ __launch_bounds__(256) void transpose_cvt(
    const void* __restrict__ src, unsigned short* __restrict__ dst,
    const int* __restrict__ flag, int R, int C)
{
    __shared__ unsigned short tile[32][33];
    const int t = threadIdx.x;
    const int c = t & 31, r8 = t >> 5;
    const int bx = blockIdx.x, by = blockIdx.y;
    const int isb = *flag;
    #pragma unroll
    for (int i = 0; i < 4; ++i) {
        int r = r8 + i * 8;
        size_t idx = (size_t)(by * 32 + r) * C + bx * 32 + c;
        tile[r][c] = isb ? ((const unsigned short*)src)[idx]
                         : f2bf(((const float*)src)[idx]);
    }
    __syncthreads();
    #pragma unroll
    for (int i = 0; i < 4; ++i) {
        int r = r8 + i * 8;
        dst[(size_t)(bx * 32 + r) * R + by * 32 + c] = tile[c][r];
    }
}

// ------------------------------------------------------------- GEMM
// C(M x Ntot) = A(MxK) * B(KxN) given Bt = B^T (NxK row-major, local rows),
// bf16 in, fp32 acc. C cols written at n_base offset, row stride Ntot.
// Output: bf16 if (force_bf16 || *flag), else f32.
// 128x128 tile, BK=32, 4 waves (2x2), each wave 64x64 = 4x4 mfma 16x16x32.
__global__ __launch_bounds__(256) void gemm_bf16(
    const unsigned short* __restrict__ A,
    const unsigned short* __restrict__ Bt,
    void* __restrict__ C,
    int M, int Ntot, int K, int n_base,
    const int* __restrict__ flag, int force_bf16)
{
    __shared__ __align__(16) unsigned short As[128 * 40];
    __shared__ __align__(16) unsigned short Bs[128 * 40];
    const int tid = threadIdx.x;
    const int n0 = blockIdx.x * 128;
    const int m0 = blockIdx.y * 128;
    const int wave = tid >> 6;
    const int lane = tid & 63;
    const int wm = (wave >> 1) * 64;
    const int wn = (wave & 1) * 64;
    const int quad = lane >> 4;
    const int l16 = lane & 15;
    const int obf = force_bf16 | *flag;

    f32x4 acc[4][4];
    #pragma unroll
    for (int i = 0; i < 4; ++i)
        #pragma unroll
        for (int j = 0; j < 4; ++j)
            acc[i][j] = f32x4{0.f, 0.f, 0.f, 0.f};

    for (int kk = 0; kk < K; kk += 32) {
        #pragma unroll
        for (int i = 0; i < 2; ++i) {
            int ch = tid + i * 256;
            int row = ch >> 2;
            int ko = (ch & 3) * 8;
            *(uint4*)&As[row * 40 + ko] =
                *(const uint4*)&A[(size_t)(m0 + row) * K + kk + ko];
            *(uint4*)&Bs[row * 40 + ko] =
                *(const uint4*)&Bt[(size_t)(n0 + row) * K + kk + ko];
        }
        __syncthreads();
        bf16x8 af[4], bfr[4];
        #pragma unroll
        for (int mi = 0; mi < 4; ++mi)
            af[mi] = *(const bf16x8*)&As[(wm + mi * 16 + l16) * 40 + quad * 8];
        #pragma unroll
        for (int ni = 0; ni < 4; ++ni)
            bfr[ni] = *(const bf16x8*)&Bs[(wn + ni * 16 + l16) * 40 + quad * 8];
        #pragma unroll
        for (int mi = 0; mi < 4; ++mi)
            #pragma unroll
            for (int ni = 0; ni < 4; ++ni)
                acc[mi][ni] = __builtin_amdgcn_mfma_f32_16x16x32_bf16(
                    af[mi], bfr[ni], acc[mi][ni], 0, 0, 0);
        __syncthreads();
    }

    #pragma unroll
    for (int mi = 0; mi < 4; ++mi)
        #pragma unroll
        for (int ni = 0; ni < 4; ++ni)
            #pragma unroll
            for (int r = 0; r < 4; ++r) {
                int row = m0 + wm + mi * 16 + quad * 4 + r;
                int col = n_base + n0 + wn + ni * 16 + l16;
                size_t idx = (size_t)row * Ntot + col;
                if (obf) ((unsigned short*)C)[idx] = f2bf(acc[mi][ni][r]);
                else     ((float*)C)[idx]          = acc[mi][ni][r];
            }
}

// ------------------------------------------------------------- finalize
// In-place RMSNorm + RoPE on q (slots 0..7) and k (slots 8..11) columns of
// qkv rows [q 8x256 | k 4x256 | v 4x256]; v untouched. One wave per slot.
__global__ __launch_bounds__(256) void finalize_qk(
    unsigned short* __restrict__ qkv,
    const int* __restrict__ segment_pos,
    const unsigned short* __restrict__ scales)   // [0:256)=q, [256:512)=k
{
    const int w = blockIdx.x * 4 + (threadIdx.x >> 6);
    const int lane = threadIdx.x & 63;
    const int b = w / (T_SEQ * 12);
    const int rem = w % (T_SEQ * 12);
    const int t = rem / 12;
    const int slot = rem % 12;
    const bool isq = slot < 8;
    const int col0 = isq ? slot * 256 : 2048 + (slot - 8) * 256;
    unsigned short* p = qkv + (size_t)(b * T_SEQ + t) * 4096 + col0;

    float e[4];
    #pragma unroll
    for (int j = 0; j < 4; ++j) e[j] = bf2f(p[lane + 64 * j]);
    float ss = e[0] * e[0] + e[1] * e[1] + e[2] * e[2] + e[3] * e[3];
    #pragma unroll
    for (int o = 32; o >= 1; o >>= 1) ss += __shfl_xor(ss, o);
    const float rn = rsqrtf(ss * (1.0f / 256.0f) + 1e-6f);
    const unsigned short* scp = scales + (isq ? 0 : 256);
    float nrm[4];
    #pragma unroll
    for (int j = 0; j < 4; ++j)
        nrm[j] = e[j] * rn * (1.0f + bf2f(scp[lane + 64 * j]));

    const int pos = segment_pos[b * T_SEQ + t];
    #pragma unroll
    for (int pp = 0; pp < 2; ++pp) {
        const int i = lane + 64 * pp;              // rope freq index < 128
        const float inv_ts = expf((float)i * -0.07195578415606293f); // 10000^(-i/128)
        float s, c;
        sincosf((float)pos * inv_ts, &s, &c);
        const float x1 = nrm[pp], x2 = nrm[pp + 2]; // pair (i, i+128)
        p[i]       = f2bf(x1 * c - x2 * s);
        p[i + 128] = f2bf(x2 * c + x1 * s);
    }
}

// ------------------------------------------------------------- attention
// one wave per (b, h, t); online softmax over window [max(0,t-511), t].
// Reads q/k/v in place from qkv rows.
__global__ __launch_bounds__(256) void attn_kernel(
    const unsigned short* __restrict__ qkv,
    unsigned short* __restrict__ out)
{
    const int w = blockIdx.x * 4 + (threadIdx.x >> 6);
    const int lane = threadIdx.x & 63;
    const int t = w & (T_SEQ - 1);
    const int bh = w >> 11;
    const int h = bh & (NHEADS - 1);
    const int b = bh >> 3;
    const int kvh = h >> 1;   // g = 2

    const ushort4 qu = *(const ushort4*)(
        qkv + (size_t)(b * T_SEQ + t) * 4096 + h * 256 + lane * 4);
    const float qs = 1.0f / 800.0f;   // HEAD_DIM^-0.5 / SOFT_CAP
    const float q0 = bf2f(qu.x) * qs, q1 = bf2f(qu.y) * qs;
    const float q2 = bf2f(qu.z) * qs, q3 = bf2f(qu.w) * qs;

    int s0 = t - (WIN - 1); if (s0 < 0) s0 = 0;
    float m = -3.0e38f, l = 0.f, a0 = 0.f, a1 = 0.f, a2 = 0.f, a3 = 0.f;
    const size_t kbase = (size_t)b * (T_SEQ * 4096) + 2048 + kvh * 256 + lane * 4;
    for (int s = s0; s <= t; ++s) {
        const size_t off = kbase + (size_t)s * 4096;
        const ushort4 ku = *(const ushort4*)(qkv + off);
        float d = q0 * bf2f(ku.x) + q1 * bf2f(ku.y)
                + q2 * bf2f(ku.z) + q3 * bf2f(ku.w);
        #pragma unroll
        for (int o = 32; o >= 1; o >>= 1) d += __shfl_xor(d, o);
        const float soft = 50.0f * tanhf(d);       // d = logits/SOFT_CAP
        const float mn = fmaxf(m, soft);
        const float alpha = __expf(m - mn);
        const float p = __expf(soft - mn);
        const ushort4 vu = *(const ushort4*)(qkv + off + 1024);
        l = l * alpha + p;
        a0 = a0 * alpha + p * bf2f(vu.x);
        a1 = a1 * alpha + p * bf2f(vu.y);
        a2 = a2 * alpha + p * bf2f(vu.z);
        a3 = a3 * alpha + p * bf2f(vu.w);
        m = mn;
    }
    const float inv = 1.0f / l;
    unsigned short* op = out + (size_t)(b * T_SEQ + t) * 2048 + h * 256 + lane * 4;
    *(ushort4*)op = make_ushort4(f2bf(a0 * inv), f2bf(a1 * inv),
                                 f2bf(a2 * inv), f2bf(a3 * inv));
}

// ------------------------------------------------------------- launch
// ws usage: 4KB (flag+scales) + 16MB (region1: xhat -> abuf)
//           + 8MB (region2: wq^T -> wkv^T -> wo^T)  = 25.2 MB total.
// qkv (4096x4096 bf16 = 32MB) lives in d_out (8.4M f32 = 33.55MB, dead
// until GEMM2's final write).
extern "C" void kernel_launch(void* const* d_in, const int* in_sizes, int n_in,
                              void* d_out, int out_size, void* d_ws, size_t ws_size,
                              hipStream_t stream) {
    const void* x   = d_in[0];
    const int*  sp  = (const int*)d_in[1];
    // d_in[2] = cur_ind (0; T == S_CACHE so caches fully overwritten)
    const void* wq  = d_in[3];
    const void* wk  = d_in[4];
    const void* wv  = d_in[5];
    const void* wo  = d_in[6];
    const void* qsc = d_in[7];
    const void* ksc = d_in[8];

    unsigned short* ws = (unsigned short*)d_ws;
    int*            flag = (int*)ws;                       // 4 B
    unsigned short* sbuf = ws + 1024;                      // 512 ushorts
    unsigned short* reg1 = ws + 2048;                      // 8,388,608 ushorts
    unsigned short* reg2 = reg1 + (size_t)4096 * 2048;     // 4,194,304 ushorts
    unsigned short* xhat = reg1;
    unsigned short* abuf = reg1;                           // after GEMM1
    unsigned short* qkv  = (unsigned short*)d_out;         // 16,777,216 ushorts

    dim3 blk(256);
    detect_dtype<<<1, 64, 0, stream>>>((const unsigned short*)x, flag);

    convert_to_bf16<<<4096, blk, 0, stream>>>(x,   xhat,       flag, 4096 * 2048);
    convert_to_bf16<<<1,    blk, 0, stream>>>(qsc, sbuf,       flag, 256);
    convert_to_bf16<<<1,    blk, 0, stream>>>(ksc, sbuf + 256, flag, 256);

    // GEMM1 pass a: q columns [0, 2048)
    transpose_cvt<<<dim3(64, 64), blk, 0, stream>>>(wq, reg2, flag, 2048, 2048);
    gemm_bf16<<<dim3(16, 32), blk, 0, stream>>>(xhat, reg2, qkv,
                                                4096, 4096, 2048, 0, flag, 1);
    // GEMM1 pass b: k,v columns [2048, 4096)
    transpose_cvt<<<dim3(32, 64), blk, 0, stream>>>(wk, reg2,                    flag, 2048, 1024);
    transpose_cvt<<<dim3(32, 64), blk, 0, stream>>>(wv, reg2 + (size_t)1024*2048, flag, 2048, 1024);
    gemm_bf16<<<dim3(16, 32), blk, 0, stream>>>(xhat, reg2, qkv,
                                                4096, 4096, 2048, 2048, flag, 1);

    finalize_qk<<<12288, blk, 0, stream>>>(qkv, sp, sbuf);
    attn_kernel<<<8192, blk, 0, stream>>>(qkv, abuf);   // abuf overwrites xhat

    // wo^T into reg2 (GEMM1 done), then GEMM2 -> d_out (f32 when flag=0)
    transpose_cvt<<<dim3(64, 64), blk, 0, stream>>>(wo, reg2, flag, 2048, 2048);
    gemm_bf16<<<dim3(16, 32), blk, 0, stream>>>(abuf, reg2, d_out,
                                                4096, 2048, 2048, 0, flag, 0);
}

// Round 5
// 531.145 us; speedup vs baseline: 3.4332x; 3.4332x over previous
//
#include <hip/hip_runtime.h>

#define T_SEQ 2048
#define NHEADS 8
#define NKV 4
#define HD 256
#define WIN 512

typedef __bf16 bf16x8 __attribute__((ext_vector_type(8)));
typedef float f32x4 __attribute__((ext_vector_type(4)));

__device__ __forceinline__ float bf2f(unsigned short u) {
    return __uint_as_float(((unsigned int)u) << 16);
}
__device__ __forceinline__ unsigned short f2bf(float f) {
    unsigned int u = __float_as_uint(f);
    u += 0x7fffu + ((u >> 16) & 1u);
    return (unsigned short)(u >> 16);
}

// ------------------------------------------------------------- dtype detect
__global__ void detect_dtype(const unsigned short* __restrict__ x, int* flag) {
    int tid = threadIdx.x;
    int cnt = 0;
    for (int i = 0; i < 64; ++i) {
        unsigned short u = x[2 * (tid * 64 + i)];
        int e = (u >> 7) & 0xFF;
        cnt += (e >= 100 && e <= 140) ? 1 : 0;
    }
    #pragma unroll
    for (int o = 32; o >= 1; o >>= 1) cnt += __shfl_xor(cnt, o);
    if (tid == 0) *flag = (cnt > 2048) ? 1 : 0;
}

// ------------------------------------------------------------- convert
__global__ __launch_bounds__(256) void convert_to_bf16(
    const void* __restrict__ src, unsigned short* __restrict__ dst,
    const int* __restrict__ flag, int n)
{
    int i = (blockIdx.x * 256 + threadIdx.x) * 8;
    if (i >= n) return;
    if (*flag) {
        *(uint4*)&dst[i] = *(const uint4*)((const unsigned short*)src + i);
    } else {
        const float* s = (const float*)src + i;
        unsigned short v[8];
        #pragma unroll
        for (int j = 0; j < 8; ++j) v[j] = f2bf(s[j]);
        *(uint4*)&dst[i] = *(uint4*)v;
    }
}

// ------------------------------------------------------------- transpose+cvt
__global__ __launch_bounds__(256) void transpose_cvt(
    const void* __restrict__ src, unsigned short* __restrict__ dst,
    const int* __restrict__ flag, int R, int C)
{
    __shared__ unsigned short tile[32][33];
    const int t = threadIdx.x;
    const int c = t & 31, r8 = t >> 5;
    const int bx = blockIdx.x, by = blockIdx.y;
    const int isb = *flag;
    #pragma unroll
    for (int i = 0; i < 4; ++i) {
        int r = r8 + i * 8;
        size_t idx = (size_t)(by * 32 + r) * C + bx * 32 + c;
        tile[r][c] = isb ? ((const unsigned short*)src)[idx]
                         : f2bf(((const float*)src)[idx]);
    }
    __syncthreads();
    #pragma unroll
    for (int i = 0; i < 4; ++i) {
        int r = r8 + i * 8;
        dst[(size_t)(bx * 32 + r) * R + by * 32 + c] = tile[c][r];
    }
}

// ------------------------------------------------------------- GEMM
__global__ __launch_bounds__(256) void gemm_bf16(
    const unsigned short* __restrict__ A,
    const unsigned short* __restrict__ Bt,
    void* __restrict__ C,
    int M, int Ntot, int K, int n_base,
    const int* __restrict__ flag, int force_bf16)
{
    __shared__ __align__(16) unsigned short As[128 * 40];
    __shared__ __align__(16) unsigned short Bs[128 * 40];
    const int tid = threadIdx.x;
    const int n0 = blockIdx.x * 128;
    const int m0 = blockIdx.y * 128;
    const int wave = tid >> 6;
    const int lane = tid & 63;
    const int wm = (wave >> 1) * 64;
    const int wn = (wave & 1) * 64;
    const int quad = lane >> 4;
    const int l16 = lane & 15;
    const int obf = force_bf16 | *flag;

    f32x4 acc[4][4];
    #pragma unroll
    for (int i = 0; i < 4; ++i)
        #pragma unroll
        for (int j = 0; j < 4; ++j)
            acc[i][j] = f32x4{0.f, 0.f, 0.f, 0.f};

    for (int kk = 0; kk < K; kk += 32) {
        #pragma unroll
        for (int i = 0; i < 2; ++i) {
            int ch = tid + i * 256;
            int row = ch >> 2;
            int ko = (ch & 3) * 8;
            *(uint4*)&As[row * 40 + ko] =
                *(const uint4*)&A[(size_t)(m0 + row) * K + kk + ko];
            *(uint4*)&Bs[row * 40 + ko] =
                *(const uint4*)&Bt[(size_t)(n0 + row) * K + kk + ko];
        }
        __syncthreads();
        bf16x8 af[4], bfr[4];
        #pragma unroll
        for (int mi = 0; mi < 4; ++mi)
            af[mi] = *(const bf16x8*)&As[(wm + mi * 16 + l16) * 40 + quad * 8];
        #pragma unroll
        for (int ni = 0; ni < 4; ++ni)
            bfr[ni] = *(const bf16x8*)&Bs[(wn + ni * 16 + l16) * 40 + quad * 8];
        #pragma unroll
        for (int mi = 0; mi < 4; ++mi)
            #pragma unroll
            for (int ni = 0; ni < 4; ++ni)
                acc[mi][ni] = __builtin_amdgcn_mfma_f32_16x16x32_bf16(
                    af[mi], bfr[ni], acc[mi][ni], 0, 0, 0);
        __syncthreads();
    }

    #pragma unroll
    for (int mi = 0; mi < 4; ++mi)
        #pragma unroll
        for (int ni = 0; ni < 4; ++ni)
            #pragma unroll
            for (int r = 0; r < 4; ++r) {
                int row = m0 + wm + mi * 16 + quad * 4 + r;
                int col = n_base + n0 + wn + ni * 16 + l16;
                size_t idx = (size_t)row * Ntot + col;
                if (obf) ((unsigned short*)C)[idx] = f2bf(acc[mi][ni][r]);
                else     ((float*)C)[idx]          = acc[mi][ni][r];
            }
}

// ------------------------------------------------------------- finalize
__global__ __launch_bounds__(256) void finalize_qk(
    unsigned short* __restrict__ qkv,
    const int* __restrict__ segment_pos,
    const unsigned short* __restrict__ scales)
{
    const int w = blockIdx.x * 4 + (threadIdx.x >> 6);
    const int lane = threadIdx.x & 63;
    const int b = w / (T_SEQ * 12);
    const int rem = w % (T_SEQ * 12);
    const int t = rem / 12;
    const int slot = rem % 12;
    const bool isq = slot < 8;
    const int col0 = isq ? slot * 256 : 2048 + (slot - 8) * 256;
    unsigned short* p = qkv + (size_t)(b * T_SEQ + t) * 4096 + col0;

    float e[4];
    #pragma unroll
    for (int j = 0; j < 4; ++j) e[j] = bf2f(p[lane + 64 * j]);
    float ss = e[0] * e[0] + e[1] * e[1] + e[2] * e[2] + e[3] * e[3];
    #pragma unroll
    for (int o = 32; o >= 1; o >>= 1) ss += __shfl_xor(ss, o);
    const float rn = rsqrtf(ss * (1.0f / 256.0f) + 1e-6f);
    const unsigned short* scp = scales + (isq ? 0 : 256);
    float nrm[4];
    #pragma unroll
    for (int j = 0; j < 4; ++j)
        nrm[j] = e[j] * rn * (1.0f + bf2f(scp[lane + 64 * j]));

    const int pos = segment_pos[b * T_SEQ + t];
    #pragma unroll
    for (int pp = 0; pp < 2; ++pp) {
        const int i = lane + 64 * pp;
        const float inv_ts = expf((float)i * -0.07195578415606293f);
        float s, c;
        sincosf((float)pos * inv_ts, &s, &c);
        const float x1 = nrm[pp], x2 = nrm[pp + 2];
        p[i]       = f2bf(x1 * c - x2 * s);
        p[i + 128] = f2bf(x2 * c + x1 * s);
    }
}

// ------------------------------------------------------------- V transpose
// vt[bkv][d][s] = qkv v-part [(b*T+s)*4096 + 3072 + kv*256 + d]
__global__ __launch_bounds__(256) void build_vt(
    const unsigned short* __restrict__ qkv, unsigned short* __restrict__ vt)
{
    __shared__ unsigned short tile[32][33];
    const int bkv = blockIdx.z;
    const int b = bkv >> 2, kv = bkv & 3;
    const int s0 = blockIdx.x * 32, d0 = blockIdx.y * 32;
    const int c = threadIdx.x & 31, r8 = threadIdx.x >> 5;
    #pragma unroll
    for (int i = 0; i < 4; ++i) {
        int r = r8 + i * 8;
        tile[r][c] = qkv[(size_t)(b * T_SEQ + s0 + r) * 4096 + 3072 + kv * 256 + d0 + c];
    }
    __syncthreads();
    #pragma unroll
    for (int i = 0; i < 4; ++i) {
        int r = r8 + i * 8;
        vt[((size_t)bkv * 256 + d0 + r) * T_SEQ + s0 + c] = tile[c][r];
    }
}

// ------------------------------------------------------------- MFMA attention
// block = (b, kvh, 32 q-positions) x 2 heads; 4 waves, wave = head x 16 queries.
// Per 64-key tile: S^T = K·Q^T (MFMA), mask+softcap+online softmax,
// P->LDS [query][key], O += P·V^T (MFMA).
#define KSTR 264   // K_lds row stride (256 + 8)
#define VSTR 72    // VT_lds / P_lds row stride (64 + 8)
__global__ __launch_bounds__(256) void attn_mfma(
    const unsigned short* __restrict__ qkv,
    const unsigned short* __restrict__ vt,
    unsigned short* __restrict__ out)
{
    __shared__ __align__(16) unsigned short K_lds[64 * KSTR];    // 33792 us
    __shared__ __align__(16) unsigned short VT_lds[256 * VSTR];  // 18432 us
    __shared__ __align__(16) unsigned short P_lds[4][16 * VSTR]; // 4x1152 us

    const int tid = threadIdx.x;
    const int wave = tid >> 6, lane = tid & 63;
    const int l16 = lane & 15, quad = lane >> 4;
    const int bkv = blockIdx.y;
    const int b = bkv >> 2, kvh = bkv & 3;
    const int t0 = blockIdx.x * 32;
    const int h = kvh * 2 + (wave >> 1);
    const int woff = (wave & 1) * 16;
    const int tq = t0 + woff + l16;            // this lane's query position

    // Q B-frags in registers: Q[tq][32c + quad*8 + j]
    bf16x8 qf[8];
    {
        const unsigned short* qp =
            qkv + (size_t)(b * T_SEQ + tq) * 4096 + h * 256 + quad * 8;
        #pragma unroll
        for (int c = 0; c < 8; ++c) qf[c] = *(const bf16x8*)(qp + 32 * c);
    }

    f32x4 o[16];
    #pragma unroll
    for (int nt = 0; nt < 16; ++nt) o[nt] = f32x4{0.f, 0.f, 0.f, 0.f};
    float m_run = -3.0e38f, l_run = 0.f;

    int s_lo = t0 - (WIN - 1); if (s_lo < 0) s_lo = 0;
    const int s_base = s_lo & ~63;
    const size_t kgbase = (size_t)b * T_SEQ * 4096 + 2048 + kvh * 256;
    const size_t vgbase = (size_t)bkv * 256 * T_SEQ;

    for (int sb = s_base; sb <= t0 + 31; sb += 64) {
        __syncthreads();
        // stage K tile: 64 rows x 256 d
        #pragma unroll
        for (int i = 0; i < 8; ++i) {
            int ch = tid + 256 * i;
            int row = ch >> 5, dcol = (ch & 31) * 8;
            *(uint4*)&K_lds[row * KSTR + dcol] =
                *(const uint4*)&qkv[kgbase + (size_t)(sb + row) * 4096 + dcol];
        }
        // stage V^T tile: 256 rows(d) x 64 s
        #pragma unroll
        for (int i = 0; i < 8; ++i) {
            int ch = tid + 256 * i;
            int drow = ch >> 3, scol = (ch & 7) * 8;
            *(uint4*)&VT_lds[drow * VSTR + scol] =
                *(const uint4*)&vt[vgbase + (size_t)drow * T_SEQ + sb + scol];
        }
        __syncthreads();

        // S^T = K · Q^T : 4 m-tiles (keys) x 1 n-tile (16 queries)
        f32x4 st[4];
        #pragma unroll
        for (int mt = 0; mt < 4; ++mt) st[mt] = f32x4{0.f, 0.f, 0.f, 0.f};
        #pragma unroll
        for (int c = 0; c < 8; ++c) {
            bf16x8 kf[4];
            #pragma unroll
            for (int mt = 0; mt < 4; ++mt)
                kf[mt] = *(const bf16x8*)&K_lds[(mt * 16 + l16) * KSTR + 32 * c + quad * 8];
            #pragma unroll
            for (int mt = 0; mt < 4; ++mt)
                st[mt] = __builtin_amdgcn_mfma_f32_16x16x32_bf16(kf[mt], qf[c], st[mt], 0, 0, 0);
        }

        // mask + softcap; running max over this tile
        float cmax = -3.0e38f;
        #pragma unroll
        for (int mt = 0; mt < 4; ++mt)
            #pragma unroll
            for (int r = 0; r < 4; ++r) {
                int sp = sb + mt * 16 + quad * 4 + r;
                float d = st[mt][r] * (1.0f / 800.0f);   // HD^-0.5 / 50
                float e2 = __expf(2.0f * d);
                float soft = 50.0f * (1.0f - 2.0f / (e2 + 1.0f));
                bool valid = (sp <= tq) && (tq - sp < WIN);
                soft = valid ? soft : -1.0e30f;
                st[mt][r] = soft;
                cmax = fmaxf(cmax, soft);
            }
        cmax = fmaxf(cmax, __shfl_xor(cmax, 16));
        cmax = fmaxf(cmax, __shfl_xor(cmax, 32));
        const float m_new = fmaxf(m_run, cmax);
        const float alpha = __expf(m_run - m_new);
        m_run = m_new;

        // P = exp(S - m); tile sum; write P^T -> P_lds[query][key]
        float tsum = 0.f;
        #pragma unroll
        for (int mt = 0; mt < 4; ++mt)
            #pragma unroll
            for (int r = 0; r < 4; ++r) {
                float p = __expf(st[mt][r] - m_new);
                tsum += p;
                P_lds[wave][l16 * VSTR + mt * 16 + quad * 4 + r] = f2bf(p);
            }
        tsum += __shfl_xor(tsum, 16);
        tsum += __shfl_xor(tsum, 32);
        l_run = l_run * alpha + tsum;

        // rescale O by alpha (per O-row query = quad*4+r)
        float al[4];
        #pragma unroll
        for (int r = 0; r < 4; ++r) al[r] = __shfl(alpha, quad * 4 + r);
        #pragma unroll
        for (int nt = 0; nt < 16; ++nt)
            #pragma unroll
            for (int r = 0; r < 4; ++r) o[nt][r] *= al[r];

        // O += P · V^T   (A = P[q][s], B = VT[s][d] via VT_lds[d][s])
        #pragma unroll
        for (int c = 0; c < 2; ++c) {
            bf16x8 pf = *(const bf16x8*)&P_lds[wave][l16 * VSTR + 32 * c + quad * 8];
            #pragma unroll
            for (int nt = 0; nt < 16; ++nt) {
                bf16x8 vf = *(const bf16x8*)&VT_lds[(nt * 16 + l16) * VSTR + 32 * c + quad * 8];
                o[nt] = __builtin_amdgcn_mfma_f32_16x16x32_bf16(pf, vf, o[nt], 0, 0, 0);
            }
        }
    }

    // normalize + write: O row query = quad*4+r, col d = nt*16+l16
    float linv[4];
    #pragma unroll
    for (int r = 0; r < 4; ++r) linv[r] = 1.0f / __shfl(l_run, quad * 4 + r);
    unsigned short* ob = out + (size_t)(b * T_SEQ + t0 + woff) * 2048 + h * 256;
    #pragma unroll
    for (int nt = 0; nt < 16; ++nt)
        #pragma unroll
        for (int r = 0; r < 4; ++r)
            ob[(size_t)(quad * 4 + r) * 2048 + nt * 16 + l16] = f2bf(o[nt][r] * linv[r]);
}

// ------------------------------------------------------------- launch
// ws: 4KB flags/scales + reg1 16MB (xhat -> abuf) + reg2 8MB
// (wq^T -> wkv^T -> vt -> wo^T). qkv lives in d_out (33.55MB f32 region).
extern "C" void kernel_launch(void* const* d_in, const int* in_sizes, int n_in,
                              void* d_out, int out_size, void* d_ws, size_t ws_size,
                              hipStream_t stream) {
    const void* x   = d_in[0];
    const int*  sp  = (const int*)d_in[1];
    const void* wq  = d_in[3];
    const void* wk  = d_in[4];
    const void* wv  = d_in[5];
    const void* wo  = d_in[6];
    const void* qsc = d_in[7];
    const void* ksc = d_in[8];

    unsigned short* ws = (unsigned short*)d_ws;
    int*            flag = (int*)ws;
    unsigned short* sbuf = ws + 1024;
    unsigned short* reg1 = ws + 2048;                      // 8,388,608 us
    unsigned short* reg2 = reg1 + (size_t)4096 * 2048;     // 4,194,304 us
    unsigned short* xhat = reg1;
    unsigned short* abuf = reg1;
    unsigned short* qkv  = (unsigned short*)d_out;

    dim3 blk(256);
    detect_dtype<<<1, 64, 0, stream>>>((const unsigned short*)x, flag);

    convert_to_bf16<<<4096, blk, 0, stream>>>(x,   xhat,       flag, 4096 * 2048);
    convert_to_bf16<<<1,    blk, 0, stream>>>(qsc, sbuf,       flag, 256);
    convert_to_bf16<<<1,    blk, 0, stream>>>(ksc, sbuf + 256, flag, 256);

    transpose_cvt<<<dim3(64, 64), blk, 0, stream>>>(wq, reg2, flag, 2048, 2048);
    gemm_bf16<<<dim3(16, 32), blk, 0, stream>>>(xhat, reg2, qkv,
                                                4096, 4096, 2048, 0, flag, 1);
    transpose_cvt<<<dim3(32, 64), blk, 0, stream>>>(wk, reg2,                     flag, 2048, 1024);
    transpose_cvt<<<dim3(32, 64), blk, 0, stream>>>(wv, reg2 + (size_t)1024*2048, flag, 2048, 1024);
    gemm_bf16<<<dim3(16, 32), blk, 0, stream>>>(xhat, reg2, qkv,
                                                4096, 4096, 2048, 2048, flag, 1);

    finalize_qk<<<12288, blk, 0, stream>>>(qkv, sp, sbuf);

    build_vt<<<dim3(64, 8, 8), blk, 0, stream>>>(qkv, reg2);   // vt in reg2
    attn_mfma<<<dim3(64, 8), blk, 0, stream>>>(qkv, reg2, abuf);

    transpose_cvt<<<dim3(64, 64), blk, 0, stream>>>(wo, reg2, flag, 2048, 2048);
    gemm_bf16<<<dim3(16, 32), blk, 0, stream>>>(abuf, reg2, d_out,
                                                4096, 2048, 2048, 0, flag, 0);
}

// Round 6
// 502.951 us; speedup vs baseline: 3.6257x; 1.0561x over previous
//
#include <hip/hip_runtime.h>

#define T_SEQ 2048
#define NHEADS 8
#define NKV 4
#define HD 256
#define WIN 512

typedef __bf16 bf16x8 __attribute__((ext_vector_type(8)));
typedef float f32x4 __attribute__((ext_vector_type(4)));

__device__ __forceinline__ float bf2f(unsigned short u) {
    return __uint_as_float(((unsigned int)u) << 16);
}
__device__ __forceinline__ unsigned short f2bf(float f) {
    unsigned int u = __float_as_uint(f);
    u += 0x7fffu + ((u >> 16) & 1u);
    return (unsigned short)(u >> 16);
}

#define GLOAD_LDS16(gptr, lptr)                                            \
    __builtin_amdgcn_global_load_lds(                                      \
        (const __attribute__((address_space(1))) unsigned int*)(gptr),     \
        (__attribute__((address_space(3))) unsigned int*)(lptr), 16, 0, 0)

// ------------------------------------------------------------- dtype detect
__global__ void detect_dtype(const unsigned short* __restrict__ x, int* flag) {
    int tid = threadIdx.x;
    int cnt = 0;
    for (int i = 0; i < 64; ++i) {
        unsigned short u = x[2 * (tid * 64 + i)];
        int e = (u >> 7) & 0xFF;
        cnt += (e >= 100 && e <= 140) ? 1 : 0;
    }
    #pragma unroll
    for (int o = 32; o >= 1; o >>= 1) cnt += __shfl_xor(cnt, o);
    if (tid == 0) *flag = (cnt > 2048) ? 1 : 0;
}

// ------------------------------------------------------------- convert
__global__ __launch_bounds__(256) void convert_to_bf16(
    const void* __restrict__ src, unsigned short* __restrict__ dst,
    const int* __restrict__ flag, int n)
{
    int i = (blockIdx.x * 256 + threadIdx.x) * 8;
    if (i >= n) return;
    if (*flag) {
        *(uint4*)&dst[i] = *(const uint4*)((const unsigned short*)src + i);
    } else {
        const float* s = (const float*)src + i;
        unsigned short v[8];
        #pragma unroll
        for (int j = 0; j < 8; ++j) v[j] = f2bf(s[j]);
        *(uint4*)&dst[i] = *(uint4*)v;
    }
}

// ------------------------------------------------------------- transpose+cvt
__global__ __launch_bounds__(256) void transpose_cvt(
    const void* __restrict__ src, unsigned short* __restrict__ dst,
    const int* __restrict__ flag, int R, int C)
{
    __shared__ unsigned short tile[32][33];
    const int t = threadIdx.x;
    const int c = t & 31, r8 = t >> 5;
    const int bx = blockIdx.x, by = blockIdx.y;
    const int isb = *flag;
    #pragma unroll
    for (int i = 0; i < 4; ++i) {
        int r = r8 + i * 8;
        size_t idx = (size_t)(by * 32 + r) * C + bx * 32 + c;
        tile[r][c] = isb ? ((const unsigned short*)src)[idx]
                         : f2bf(((const float*)src)[idx]);
    }
    __syncthreads();
    #pragma unroll
    for (int i = 0; i < 4; ++i) {
        int r = r8 + i * 8;
        dst[(size_t)(bx * 32 + r) * R + by * 32 + c] = tile[c][r];
    }
}

// ------------------------------------------------------------- GEMM (m97)
// C(M x Ntot) = A(MxK) * Bt^T, bf16 in, fp32 acc. 128x128 tile, BK=32,
// async global->LDS staging (width 16), unpadded LDS (bank-balanced b128).
__global__ __launch_bounds__(256) void gemm_bf16(
    const unsigned short* __restrict__ A,
    const unsigned short* __restrict__ Bt,
    void* __restrict__ C,
    int M, int Ntot, int K, int n_base,
    const int* __restrict__ flag, int force_bf16)
{
    __shared__ __align__(16) unsigned short As[128 * 32];
    __shared__ __align__(16) unsigned short Bs[128 * 32];
    const int tid = threadIdx.x;
    const int n0 = blockIdx.x * 128;
    const int m0 = blockIdx.y * 128;
    const int wave = tid >> 6;
    const int lane = tid & 63;
    const int wm = (wave >> 1) * 64;
    const int wn = (wave & 1) * 64;
    const int quad = lane >> 4;
    const int l16 = lane & 15;
    const int obf = force_bf16 | *flag;

    f32x4 acc[4][4];
    #pragma unroll
    for (int i = 0; i < 4; ++i)
        #pragma unroll
        for (int j = 0; j < 4; ++j)
            acc[i][j] = f32x4{0.f, 0.f, 0.f, 0.f};

    for (int kk = 0; kk < K; kk += 32) {
        #pragma unroll
        for (int i = 0; i < 2; ++i) {
            int ch = tid + i * 256;            // chunk: 16B, lane-contiguous
            int row = ch >> 2;
            int ko = (ch & 3) * 8;
            GLOAD_LDS16(&A[(size_t)(m0 + row) * K + kk + ko],  &As[ch * 8]);
            GLOAD_LDS16(&Bt[(size_t)(n0 + row) * K + kk + ko], &Bs[ch * 8]);
        }
        __syncthreads();
        bf16x8 af[4], bfr[4];
        #pragma unroll
        for (int mi = 0; mi < 4; ++mi)
            af[mi] = *(const bf16x8*)&As[(wm + mi * 16 + l16) * 32 + quad * 8];
        #pragma unroll
        for (int ni = 0; ni < 4; ++ni)
            bfr[ni] = *(const bf16x8*)&Bs[(wn + ni * 16 + l16) * 32 + quad * 8];
        #pragma unroll
        for (int mi = 0; mi < 4; ++mi)
            #pragma unroll
            for (int ni = 0; ni < 4; ++ni)
                acc[mi][ni] = __builtin_amdgcn_mfma_f32_16x16x32_bf16(
                    af[mi], bfr[ni], acc[mi][ni], 0, 0, 0);
        __syncthreads();
    }

    #pragma unroll
    for (int mi = 0; mi < 4; ++mi)
        #pragma unroll
        for (int ni = 0; ni < 4; ++ni)
            #pragma unroll
            for (int r = 0; r < 4; ++r) {
                int row = m0 + wm + mi * 16 + quad * 4 + r;
                int col = n_base + n0 + wn + ni * 16 + l16;
                size_t idx = (size_t)row * Ntot + col;
                if (obf) ((unsigned short*)C)[idx] = f2bf(acc[mi][ni][r]);
                else     ((float*)C)[idx]          = acc[mi][ni][r];
            }
}

// ------------------------------------------------------------- finalize
__global__ __launch_bounds__(256) void finalize_qk(
    unsigned short* __restrict__ qkv,
    const int* __restrict__ segment_pos,
    const unsigned short* __restrict__ scales)
{
    const int w = blockIdx.x * 4 + (threadIdx.x >> 6);
    const int lane = threadIdx.x & 63;
    const int b = w / (T_SEQ * 12);
    const int rem = w % (T_SEQ * 12);
    const int t = rem / 12;
    const int slot = rem % 12;
    const bool isq = slot < 8;
    const int col0 = isq ? slot * 256 : 2048 + (slot - 8) * 256;
    unsigned short* p = qkv + (size_t)(b * T_SEQ + t) * 4096 + col0;

    float e[4];
    #pragma unroll
    for (int j = 0; j < 4; ++j) e[j] = bf2f(p[lane + 64 * j]);
    float ss = e[0] * e[0] + e[1] * e[1] + e[2] * e[2] + e[3] * e[3];
    #pragma unroll
    for (int o = 32; o >= 1; o >>= 1) ss += __shfl_xor(ss, o);
    const float rn = rsqrtf(ss * (1.0f / 256.0f) + 1e-6f);
    const unsigned short* scp = scales + (isq ? 0 : 256);
    float nrm[4];
    #pragma unroll
    for (int j = 0; j < 4; ++j)
        nrm[j] = e[j] * rn * (1.0f + bf2f(scp[lane + 64 * j]));

    const int pos = segment_pos[b * T_SEQ + t];
    #pragma unroll
    for (int pp = 0; pp < 2; ++pp) {
        const int i = lane + 64 * pp;
        const float inv_ts = __expf((float)i * -0.07195578415606293f);
        float s, c;
        __sincosf((float)pos * inv_ts, &s, &c);
        const float x1 = nrm[pp], x2 = nrm[pp + 2];
        p[i]       = f2bf(x1 * c - x2 * s);
        p[i + 128] = f2bf(x2 * c + x1 * s);
    }
}

// ------------------------------------------------------------- V transpose
__global__ __launch_bounds__(256) void build_vt(
    const unsigned short* __restrict__ qkv, unsigned short* __restrict__ vt)
{
    __shared__ unsigned short tile[32][33];
    const int bkv = blockIdx.z;
    const int b = bkv >> 2, kv = bkv & 3;
    const int s0 = blockIdx.x * 32, d0 = blockIdx.y * 32;
    const int c = threadIdx.x & 31, r8 = threadIdx.x >> 5;
    #pragma unroll
    for (int i = 0; i < 4; ++i) {
        int r = r8 + i * 8;
        tile[r][c] = qkv[(size_t)(b * T_SEQ + s0 + r) * 4096 + 3072 + kv * 256 + d0 + c];
    }
    __syncthreads();
    #pragma unroll
    for (int i = 0; i < 4; ++i) {
        int r = r8 + i * 8;
        vt[((size_t)bkv * 256 + d0 + r) * T_SEQ + s0 + c] = tile[c][r];
    }
}

// ------------------------------------------------------------- MFMA attention
// Static-max flash attention (softcap bounds logits; m = 30 provably safe).
// Register-prefetched K/V staging; XOR-swizzled LDS (bank-balanced).
#define PSTR 72
__global__ __launch_bounds__(256, 2) void attn_mfma(
    const unsigned short* __restrict__ qkv,
    const unsigned short* __restrict__ vt,
    unsigned short* __restrict__ out)
{
    __shared__ __align__(16) unsigned short K_lds[64 * 256];     // 32 KB
    __shared__ __align__(16) unsigned short VT_lds[256 * 64];    // 32 KB
    __shared__ __align__(16) unsigned short P_lds[4][16 * PSTR]; // 9 KB

    const int tid = threadIdx.x;
    const int wave = tid >> 6, lane = tid & 63;
    const int l16 = lane & 15, quad = lane >> 4;
    const int sw = l16 & 7;
    const int bkv = blockIdx.y;
    const int b = bkv >> 2, kvh = bkv & 3;
    const int t0 = blockIdx.x * 32;
    const int h = kvh * 2 + (wave >> 1);
    const int woff = (wave & 1) * 16;
    const int tq = t0 + woff + l16;

    bf16x8 qf[8];
    {
        const unsigned short* qp =
            qkv + (size_t)(b * T_SEQ + tq) * 4096 + h * 256 + quad * 8;
        #pragma unroll
        for (int c = 0; c < 8; ++c) qf[c] = *(const bf16x8*)(qp + 32 * c);
    }

    f32x4 o[16];
    #pragma unroll
    for (int nt = 0; nt < 16; ++nt) o[nt] = f32x4{0.f, 0.f, 0.f, 0.f};
    float l_run = 0.f;

    int s_lo = t0 - (WIN - 1); if (s_lo < 0) s_lo = 0;
    const int s_base = s_lo & ~63;
    const int s_last = t0 + 31;
    const size_t kgbase = (size_t)b * T_SEQ * 4096 + 2048 + kvh * 256;
    const size_t vgbase = (size_t)bkv * 256 * T_SEQ;

    uint4 ka[8], va[8];
    #pragma unroll
    for (int i = 0; i < 8; ++i) {
        int ch = tid + 256 * i;
        ka[i] = *(const uint4*)&qkv[kgbase + (size_t)(s_base + (ch >> 5)) * 4096 + (ch & 31) * 8];
        va[i] = *(const uint4*)&vt[vgbase + (size_t)(ch >> 3) * T_SEQ + s_base + (ch & 7) * 8];
    }

    for (int sb = s_base; sb <= s_last; sb += 64) {
        __syncthreads();
        #pragma unroll
        for (int i = 0; i < 8; ++i) {
            int ch = tid + 256 * i;
            int row = ch >> 5, d8 = ch & 31;
            *(uint4*)&K_lds[row * 256 + ((d8 ^ (row & 7)) * 8)] = ka[i];
            int dr = ch >> 3, s8 = ch & 7;
            *(uint4*)&VT_lds[dr * 64 + ((s8 ^ (dr & 7)) * 8)] = va[i];
        }
        __syncthreads();

        // prefetch next tile into registers (hidden under compute)
        const int nsb = (sb + 64 <= s_last) ? sb + 64 : sb;
        #pragma unroll
        for (int i = 0; i < 8; ++i) {
            int ch = tid + 256 * i;
            ka[i] = *(const uint4*)&qkv[kgbase + (size_t)(nsb + (ch >> 5)) * 4096 + (ch & 31) * 8];
            va[i] = *(const uint4*)&vt[vgbase + (size_t)(ch >> 3) * T_SEQ + nsb + (ch & 7) * 8];
        }

        // S^T = K · Q^T
        f32x4 st[4];
        #pragma unroll
        for (int mt = 0; mt < 4; ++mt) st[mt] = f32x4{0.f, 0.f, 0.f, 0.f};
        #pragma unroll
        for (int c = 0; c < 8; ++c) {
            bf16x8 kf[4];
            #pragma unroll
            for (int mt = 0; mt < 4; ++mt)
                kf[mt] = *(const bf16x8*)&K_lds[(mt * 16 + l16) * 256 + (((4 * c + quad) ^ sw) * 8)];
            #pragma unroll
            for (int mt = 0; mt < 4; ++mt)
                st[mt] = __builtin_amdgcn_mfma_f32_16x16x32_bf16(kf[mt], qf[c], st[mt], 0, 0, 0);
        }

        // softcap + exp(static m=30); accumulate per-lane l; P -> LDS
        #pragma unroll
        for (int mt = 0; mt < 4; ++mt)
            #pragma unroll
            for (int r = 0; r < 4; ++r) {
                int sp = sb + mt * 16 + quad * 4 + r;
                float e2 = __expf(st[mt][r] * 0.0025f);        // exp(2*logits/(16*50))
                float p = __expf(20.0f - 100.0f / (e2 + 1.0f)); // exp(softcap - 30)
                bool valid = (sp <= tq) && (tq - sp < WIN);
                p = valid ? p : 0.0f;
                l_run += p;
                P_lds[wave][l16 * PSTR + mt * 16 + quad * 4 + r] = f2bf(p);
            }

        // O += P · V^T
        #pragma unroll
        for (int c = 0; c < 2; ++c) {
            bf16x8 pf = *(const bf16x8*)&P_lds[wave][l16 * PSTR + 32 * c + quad * 8];
            #pragma unroll
            for (int nt = 0; nt < 16; ++nt) {
                bf16x8 vf = *(const bf16x8*)&VT_lds[(nt * 16 + l16) * 64 + (((4 * c + quad) ^ sw) * 8)];
                o[nt] = __builtin_amdgcn_mfma_f32_16x16x32_bf16(pf, vf, o[nt], 0, 0, 0);
            }
        }
    }

    l_run += __shfl_xor(l_run, 16);
    l_run += __shfl_xor(l_run, 32);
    float linv[4];
    #pragma unroll
    for (int r = 0; r < 4; ++r) linv[r] = 1.0f / __shfl(l_run, quad * 4 + r);
    unsigned short* ob = out + (size_t)(b * T_SEQ + t0 + woff) * 2048 + h * 256;
    #pragma unroll
    for (int nt = 0; nt < 16; ++nt)
        #pragma unroll
        for (int r = 0; r < 4; ++r)
            ob[(size_t)(quad * 4 + r) * 2048 + nt * 16 + l16] = f2bf(o[nt][r] * linv[r]);
}

// ------------------------------------------------------------- launch
extern "C" void kernel_launch(void* const* d_in, const int* in_sizes, int n_in,
                              void* d_out, int out_size, void* d_ws, size_t ws_size,
                              hipStream_t stream) {
    const void* x   = d_in[0];
    const int*  sp  = (const int*)d_in[1];
    const void* wq  = d_in[3];
    const void* wk  = d_in[4];
    const void* wv  = d_in[5];
    const void* wo  = d_in[6];
    const void* qsc = d_in[7];
    const void* ksc = d_in[8];

    unsigned short* ws = (unsigned short*)d_ws;
    int*            flag = (int*)ws;
    unsigned short* sbuf = ws + 1024;
    unsigned short* reg1 = ws + 2048;                      // 8,388,608 us
    unsigned short* reg2 = reg1 + (size_t)4096 * 2048;     // 4,194,304 us
    unsigned short* xhat = reg1;
    unsigned short* abuf = reg1;
    unsigned short* qkv  = (unsigned short*)d_out;

    dim3 blk(256);
    detect_dtype<<<1, 64, 0, stream>>>((const unsigned short*)x, flag);

    convert_to_bf16<<<4096, blk, 0, stream>>>(x,   xhat,       flag, 4096 * 2048);
    convert_to_bf16<<<1,    blk, 0, stream>>>(qsc, sbuf,       flag, 256);
    convert_to_bf16<<<1,    blk, 0, stream>>>(ksc, sbuf + 256, flag, 256);

    transpose_cvt<<<dim3(64, 64), blk, 0, stream>>>(wq, reg2, flag, 2048, 2048);
    gemm_bf16<<<dim3(16, 32), blk, 0, stream>>>(xhat, reg2, qkv,
                                                4096, 4096, 2048, 0, flag, 1);
    transpose_cvt<<<dim3(32, 64), blk, 0, stream>>>(wk, reg2,                     flag, 2048, 1024);
    transpose_cvt<<<dim3(32, 64), blk, 0, stream>>>(wv, reg2 + (size_t)1024*2048, flag, 2048, 1024);
    gemm_bf16<<<dim3(16, 32), blk, 0, stream>>>(xhat, reg2, qkv,
                                                4096, 4096, 2048, 2048, flag, 1);

    finalize_qk<<<12288, blk, 0, stream>>>(qkv, sp, sbuf);

    build_vt<<<dim3(64, 8, 8), blk, 0, stream>>>(qkv, reg2);
    attn_mfma<<<dim3(64, 8), blk, 0, stream>>>(qkv, reg2, abuf);

    transpose_cvt<<<dim3(64, 64), blk, 0, stream>>>(wo, reg2, flag, 2048, 2048);
    gemm_bf16<<<dim3(16, 32), blk, 0, stream>>>(abuf, reg2, d_out,
                                                4096, 2048, 2048, 0, flag, 0);
}

// Round 7
// 480.210 us; speedup vs baseline: 3.7974x; 1.0474x over previous
//
#include <hip/hip_runtime.h>

#define T_SEQ 2048
#define NHEADS 8
#define NKV 4
#define HD 256
#define WIN 512

typedef __bf16 bf16x8 __attribute__((ext_vector_type(8)));
typedef float f32x4 __attribute__((ext_vector_type(4)));

__device__ __forceinline__ float bf2f(unsigned short u) {
    return __uint_as_float(((unsigned int)u) << 16);
}
__device__ __forceinline__ unsigned short f2bf(float f) {
    unsigned int u = __float_as_uint(f);
    u += 0x7fffu + ((u >> 16) & 1u);
    return (unsigned short)(u >> 16);
}

#define GLOAD_LDS16(gptr, lptr)                                            \
    __builtin_amdgcn_global_load_lds(                                      \
        (const __attribute__((address_space(1))) unsigned int*)(gptr),     \
        (__attribute__((address_space(3))) unsigned int*)(lptr), 16, 0, 0)

// ------------------------------------------------------------- dtype detect
__global__ void detect_dtype(const unsigned short* __restrict__ x, int* flag) {
    int tid = threadIdx.x;
    int cnt = 0;
    for (int i = 0; i < 64; ++i) {
        unsigned short u = x[2 * (tid * 64 + i)];
        int e = (u >> 7) & 0xFF;
        cnt += (e >= 100 && e <= 140) ? 1 : 0;
    }
    #pragma unroll
    for (int o = 32; o >= 1; o >>= 1) cnt += __shfl_xor(cnt, o);
    if (tid == 0) *flag = (cnt > 2048) ? 1 : 0;
}

// ------------------------------------------------------------- convert
__global__ __launch_bounds__(256) void convert_to_bf16(
    const void* __restrict__ src, unsigned short* __restrict__ dst,
    const int* __restrict__ flag, int n)
{
    int i = (blockIdx.x * 256 + threadIdx.x) * 8;
    if (i >= n) return;
    if (*flag) {
        *(uint4*)&dst[i] = *(const uint4*)((const unsigned short*)src + i);
    } else {
        const float* s = (const float*)src + i;
        unsigned short v[8];
        #pragma unroll
        for (int j = 0; j < 8; ++j) v[j] = f2bf(s[j]);
        *(uint4*)&dst[i] = *(uint4*)v;
    }
}

// ------------------------------------------------------------- transpose+cvt
__global__ __launch_bounds__(256) void transpose_cvt(
    const void* __restrict__ src, unsigned short* __restrict__ dst,
    const int* __restrict__ flag, int R, int C)
{
    __shared__ unsigned short tile[32][33];
    const int t = threadIdx.x;
    const int c = t & 31, r8 = t >> 5;
    const int bx = blockIdx.x, by = blockIdx.y;
    const int isb = *flag;
    #pragma unroll
    for (int i = 0; i < 4; ++i) {
        int r = r8 + i * 8;
        size_t idx = (size_t)(by * 32 + r) * C + bx * 32 + c;
        tile[r][c] = isb ? ((const unsigned short*)src)[idx]
                         : f2bf(((const float*)src)[idx]);
    }
    __syncthreads();
    #pragma unroll
    for (int i = 0; i < 4; ++i) {
        int r = r8 + i * 8;
        dst[(size_t)(bx * 32 + r) * R + by * 32 + c] = tile[c][r];
    }
}

// ------------------------------------------------------------- GEMM (m97)
__global__ __launch_bounds__(256) void gemm_bf16(
    const unsigned short* __restrict__ A,
    const unsigned short* __restrict__ Bt,
    void* __restrict__ C,
    int M, int Ntot, int K, int n_base,
    const int* __restrict__ flag, int force_bf16)
{
    __shared__ __align__(16) unsigned short As[128 * 32];
    __shared__ __align__(16) unsigned short Bs[128 * 32];
    const int tid = threadIdx.x;
    const int n0 = blockIdx.x * 128;
    const int m0 = blockIdx.y * 128;
    const int wave = tid >> 6;
    const int lane = tid & 63;
    const int wm = (wave >> 1) * 64;
    const int wn = (wave & 1) * 64;
    const int quad = lane >> 4;
    const int l16 = lane & 15;
    const int obf = force_bf16 | *flag;

    f32x4 acc[4][4];
    #pragma unroll
    for (int i = 0; i < 4; ++i)
        #pragma unroll
        for (int j = 0; j < 4; ++j)
            acc[i][j] = f32x4{0.f, 0.f, 0.f, 0.f};

    for (int kk = 0; kk < K; kk += 32) {
        #pragma unroll
        for (int i = 0; i < 2; ++i) {
            int ch = tid + i * 256;
            int row = ch >> 2;
            int ko = (ch & 3) * 8;
            GLOAD_LDS16(&A[(size_t)(m0 + row) * K + kk + ko],  &As[ch * 8]);
            GLOAD_LDS16(&Bt[(size_t)(n0 + row) * K + kk + ko], &Bs[ch * 8]);
        }
        __syncthreads();
        bf16x8 af[4], bfr[4];
        #pragma unroll
        for (int mi = 0; mi < 4; ++mi)
            af[mi] = *(const bf16x8*)&As[(wm + mi * 16 + l16) * 32 + quad * 8];
        #pragma unroll
        for (int ni = 0; ni < 4; ++ni)
            bfr[ni] = *(const bf16x8*)&Bs[(wn + ni * 16 + l16) * 32 + quad * 8];
        #pragma unroll
        for (int mi = 0; mi < 4; ++mi)
            #pragma unroll
            for (int ni = 0; ni < 4; ++ni)
                acc[mi][ni] = __builtin_amdgcn_mfma_f32_16x16x32_bf16(
                    af[mi], bfr[ni], acc[mi][ni], 0, 0, 0);
        __syncthreads();
    }

    #pragma unroll
    for (int mi = 0; mi < 4; ++mi)
        #pragma unroll
        for (int ni = 0; ni < 4; ++ni)
            #pragma unroll
            for (int r = 0; r < 4; ++r) {
                int row = m0 + wm + mi * 16 + quad * 4 + r;
                int col = n_base + n0 + wn + ni * 16 + l16;
                size_t idx = (size_t)row * Ntot + col;
                if (obf) ((unsigned short*)C)[idx] = f2bf(acc[mi][ni][r]);
                else     ((float*)C)[idx]          = acc[mi][ni][r];
            }
}

// ------------------------------------------------------------- finalize
__global__ __launch_bounds__(256) void finalize_qk(
    unsigned short* __restrict__ qkv,
    const int* __restrict__ segment_pos,
    const unsigned short* __restrict__ scales)
{
    const int w = blockIdx.x * 4 + (threadIdx.x >> 6);
    const int lane = threadIdx.x & 63;
    const int b = w / (T_SEQ * 12);
    const int rem = w % (T_SEQ * 12);
    const int t = rem / 12;
    const int slot = rem % 12;
    const bool isq = slot < 8;
    const int col0 = isq ? slot * 256 : 2048 + (slot - 8) * 256;
    unsigned short* p = qkv + (size_t)(b * T_SEQ + t) * 4096 + col0;

    float e[4];
    #pragma unroll
    for (int j = 0; j < 4; ++j) e[j] = bf2f(p[lane + 64 * j]);
    float ss = e[0] * e[0] + e[1] * e[1] + e[2] * e[2] + e[3] * e[3];
    #pragma unroll
    for (int o = 32; o >= 1; o >>= 1) ss += __shfl_xor(ss, o);
    const float rn = rsqrtf(ss * (1.0f / 256.0f) + 1e-6f);
    const unsigned short* scp = scales + (isq ? 0 : 256);
    float nrm[4];
    #pragma unroll
    for (int j = 0; j < 4; ++j)
        nrm[j] = e[j] * rn * (1.0f + bf2f(scp[lane + 64 * j]));

    const int pos = segment_pos[b * T_SEQ + t];
    #pragma unroll
    for (int pp = 0; pp < 2; ++pp) {
        const int i = lane + 64 * pp;
        const float inv_ts = __expf((float)i * -0.07195578415606293f);
        float s, c;
        __sincosf((float)pos * inv_ts, &s, &c);
        const float x1 = nrm[pp], x2 = nrm[pp + 2];
        p[i]       = f2bf(x1 * c - x2 * s);
        p[i + 128] = f2bf(x2 * c + x1 * s);
    }
}

// ------------------------------------------------------------- V transpose
__global__ __launch_bounds__(256) void build_vt(
    const unsigned short* __restrict__ qkv, unsigned short* __restrict__ vt)
{
    __shared__ unsigned short tile[32][33];
    const int bkv = blockIdx.z;
    const int b = bkv >> 2, kv = bkv & 3;
    const int s0 = blockIdx.x * 32, d0 = blockIdx.y * 32;
    const int c = threadIdx.x & 31, r8 = threadIdx.x >> 5;
    #pragma unroll
    for (int i = 0; i < 4; ++i) {
        int r = r8 + i * 8;
        tile[r][c] = qkv[(size_t)(b * T_SEQ + s0 + r) * 4096 + 3072 + kv * 256 + d0 + c];
    }
    __syncthreads();
    #pragma unroll
    for (int i = 0; i < 4; ++i) {
        int r = r8 + i * 8;
        vt[((size_t)bkv * 256 + d0 + r) * T_SEQ + s0 + c] = tile[c][r];
    }
}

// ------------------------------------------------------------- MFMA attention
// XCD-swizzled (bkv = blockIdx&7 -> all blocks sharing K/V on one XCD's L2),
// static-max softmax, register-prefetched staging, coalesced LDS epilogue.
#define PSTR 80
__global__ __launch_bounds__(256, 2) void attn_mfma(
    const unsigned short* __restrict__ qkv,
    const unsigned short* __restrict__ vt,
    unsigned short* __restrict__ out)
{
    __shared__ __align__(16) unsigned short SMEM[16384 + 16384 + 4 * 16 * PSTR];
    unsigned short* K_lds  = SMEM;            // 64 x 256 (swizzled)
    unsigned short* VT_lds = SMEM + 16384;    // 256 x 64 (swizzled)

    const int tid = threadIdx.x;
    const int wave = tid >> 6, lane = tid & 63;
    const int l16 = lane & 15, quad = lane >> 4;
    const int sw = l16 & 7;
    const int bkv = blockIdx.x & 7;           // XCD swizzle: same bkv -> same XCD
    const int qt  = blockIdx.x >> 3;
    const int b = bkv >> 2, kvh = bkv & 3;
    const int t0 = qt * 32;
    const int h = kvh * 2 + (wave >> 1);
    const int woff = (wave & 1) * 16;
    const int tq = t0 + woff + l16;
    unsigned short* P_lds = SMEM + 32768 + wave * 16 * PSTR;

    bf16x8 qf[8];
    {
        const unsigned short* qp =
            qkv + (size_t)(b * T_SEQ + tq) * 4096 + h * 256 + quad * 8;
        #pragma unroll
        for (int c = 0; c < 8; ++c) qf[c] = *(const bf16x8*)(qp + 32 * c);
    }

    f32x4 o[16];
    #pragma unroll
    for (int nt = 0; nt < 16; ++nt) o[nt] = f32x4{0.f, 0.f, 0.f, 0.f};
    float l_run = 0.f;

    int s_lo = t0 - (WIN - 1); if (s_lo < 0) s_lo = 0;
    const int s_base = s_lo & ~63;
    const int s_last = t0 + 31;
    const int tqmin = t0 + woff;
    const int tqmax = tqmin + 15;
    const int wlo   = tqmin - (WIN - 1);      // lowest key this wave can see
    const size_t kgbase = (size_t)b * T_SEQ * 4096 + 2048 + kvh * 256;
    const size_t vgbase = (size_t)bkv * 256 * T_SEQ;

    uint4 ka[8], va[8];
    #pragma unroll
    for (int i = 0; i < 8; ++i) {
        int ch = tid + 256 * i;
        ka[i] = *(const uint4*)&qkv[kgbase + (size_t)(s_base + (ch >> 5)) * 4096 + (ch & 31) * 8];
        va[i] = *(const uint4*)&vt[vgbase + (size_t)(ch >> 3) * T_SEQ + s_base + (ch & 7) * 8];
    }

    for (int sb = s_base; sb <= s_last; sb += 64) {
        __syncthreads();
        #pragma unroll
        for (int i = 0; i < 8; ++i) {
            int ch = tid + 256 * i;
            int row = ch >> 5, d8 = ch & 31;
            *(uint4*)&K_lds[row * 256 + ((d8 ^ (row & 7)) * 8)] = ka[i];
            int dr = ch >> 3, s8 = ch & 7;
            *(uint4*)&VT_lds[dr * 64 + ((s8 ^ (dr & 7)) * 8)] = va[i];
        }
        __syncthreads();

        if (sb + 64 <= s_last) {   // block-uniform: prefetch next tile only
            #pragma unroll
            for (int i = 0; i < 8; ++i) {
                int ch = tid + 256 * i;
                ka[i] = *(const uint4*)&qkv[kgbase + (size_t)(sb + 64 + (ch >> 5)) * 4096 + (ch & 31) * 8];
                va[i] = *(const uint4*)&vt[vgbase + (size_t)(ch >> 3) * T_SEQ + sb + 64 + (ch & 7) * 8];
            }
        }

        if (sb > tqmax || sb + 63 < wlo) continue;   // wave-uniform skip

        // S^T = K · Q^T
        f32x4 st[4];
        #pragma unroll
        for (int mt = 0; mt < 4; ++mt) st[mt] = f32x4{0.f, 0.f, 0.f, 0.f};
        #pragma unroll
        for (int c = 0; c < 8; ++c) {
            bf16x8 kf[4];
            #pragma unroll
            for (int mt = 0; mt < 4; ++mt)
                kf[mt] = *(const bf16x8*)&K_lds[(mt * 16 + l16) * 256 + (((4 * c + quad) ^ sw) * 8)];
            #pragma unroll
            for (int mt = 0; mt < 4; ++mt)
                st[mt] = __builtin_amdgcn_mfma_f32_16x16x32_bf16(kf[mt], qf[c], st[mt], 0, 0, 0);
        }

        // softcap + exp(static m=30); P -> LDS
        #pragma unroll
        for (int mt = 0; mt < 4; ++mt)
            #pragma unroll
            for (int r = 0; r < 4; ++r) {
                int sp = sb + mt * 16 + quad * 4 + r;
                float e2 = __expf(st[mt][r] * 0.0025f);         // exp(2*logits/800)
                float p = __expf(20.0f - 100.0f / (e2 + 1.0f)); // exp(softcap - 30)
                bool valid = (sp <= tq) && (tq - sp < WIN);
                p = valid ? p : 0.0f;
                l_run += p;
                P_lds[l16 * PSTR + mt * 16 + quad * 4 + r] = f2bf(p);
            }

        // O += P · V^T
        #pragma unroll
        for (int c = 0; c < 2; ++c) {
            bf16x8 pf = *(const bf16x8*)&P_lds[l16 * PSTR + 32 * c + quad * 8];
            #pragma unroll
            for (int nt = 0; nt < 16; ++nt) {
                bf16x8 vf = *(const bf16x8*)&VT_lds[(nt * 16 + l16) * 64 + (((4 * c + quad) ^ sw) * 8)];
                o[nt] = __builtin_amdgcn_mfma_f32_16x16x32_bf16(pf, vf, o[nt], 0, 0, 0);
            }
        }
    }

    l_run += __shfl_xor(l_run, 16);
    l_run += __shfl_xor(l_run, 32);
    float linv[4];
    #pragma unroll
    for (int r = 0; r < 4; ++r) linv[r] = 1.0f / __shfl(l_run, quad * 4 + r);

    // coalesced epilogue: O -> LDS (row-major 16x256, stride 264) -> dwordx4
    __syncthreads();
    unsigned short* W = SMEM + wave * (16 * 264);
    #pragma unroll
    for (int nt = 0; nt < 16; ++nt)
        #pragma unroll
        for (int r = 0; r < 4; ++r)
            W[(quad * 4 + r) * 264 + nt * 16 + l16] = f2bf(o[nt][r] * linv[r]);
    const int lr = lane >> 2, lc = (lane & 3) * 64;
    unsigned short* ob = out + (size_t)(b * T_SEQ + t0 + woff + lr) * 2048 + h * 256 + lc;
    #pragma unroll
    for (int j = 0; j < 8; ++j)
        *(uint4*)(ob + j * 8) = *(const uint4*)&W[lr * 264 + lc + j * 8];
}

// ------------------------------------------------------------- launch
extern "C" void kernel_launch(void* const* d_in, const int* in_sizes, int n_in,
                              void* d_out, int out_size, void* d_ws, size_t ws_size,
                              hipStream_t stream) {
    const void* x   = d_in[0];
    const int*  sp  = (const int*)d_in[1];
    const void* wq  = d_in[3];
    const void* wk  = d_in[4];
    const void* wv  = d_in[5];
    const void* wo  = d_in[6];
    const void* qsc = d_in[7];
    const void* ksc = d_in[8];

    unsigned short* ws = (unsigned short*)d_ws;
    int*            flag = (int*)ws;
    unsigned short* sbuf = ws + 1024;
    unsigned short* reg1 = ws + 2048;                      // 8,388,608 us
    unsigned short* reg2 = reg1 + (size_t)4096 * 2048;     // 4,194,304 us
    unsigned short* xhat = reg1;
    unsigned short* abuf = reg1;
    unsigned short* qkv  = (unsigned short*)d_out;

    dim3 blk(256);
    detect_dtype<<<1, 64, 0, stream>>>((const unsigned short*)x, flag);

    convert_to_bf16<<<4096, blk, 0, stream>>>(x,   xhat,       flag, 4096 * 2048);
    convert_to_bf16<<<1,    blk, 0, stream>>>(qsc, sbuf,       flag, 256);
    convert_to_bf16<<<1,    blk, 0, stream>>>(ksc, sbuf + 256, flag, 256);

    transpose_cvt<<<dim3(64, 64), blk, 0, stream>>>(wq, reg2, flag, 2048, 2048);
    gemm_bf16<<<dim3(16, 32), blk, 0, stream>>>(xhat, reg2, qkv,
                                                4096, 4096, 2048, 0, flag, 1);
    transpose_cvt<<<dim3(32, 64), blk, 0, stream>>>(wk, reg2,                     flag, 2048, 1024);
    transpose_cvt<<<dim3(32, 64), blk, 0, stream>>>(wv, reg2 + (size_t)1024*2048, flag, 2048, 1024);
    gemm_bf16<<<dim3(16, 32), blk, 0, stream>>>(xhat, reg2, qkv,
                                                4096, 4096, 2048, 2048, flag, 1);

    finalize_qk<<<12288, blk, 0, stream>>>(qkv, sp, sbuf);

    build_vt<<<dim3(64, 8, 8), blk, 0, stream>>>(qkv, reg2);
    attn_mfma<<<512, blk, 0, stream>>>(qkv, reg2, abuf);

    transpose_cvt<<<dim3(64, 64), blk, 0, stream>>>(wo, reg2, flag, 2048, 2048);
    gemm_bf16<<<dim3(16, 32), blk, 0, stream>>>(abuf, reg2, d_out,
                                                4096, 2048, 2048, 0, flag, 0);
}